// Round 31
// baseline (3754.620 us; speedup 1.0000x reference)
//
#include <hip/hip_runtime.h>
#include <hip/hip_bf16.h>

// LSTM: T=8192, IN=3000, H=100 (4H=400), torch gate order i,f,g,o.
// ROUND-31: worker-count dial pays ~35us per halving (255->127->63:
// 3767->3733->3698), mechanism = burst-contention on the scan's xg loads.
// Next step: NWORK 63 -> 31. GEMM stretches to ~2.4ms, still < 3.5ms scan
// (production ~2 chunks/25us vs consumption 1 chunk/55us -> no waits after
// chunk 0). All else byte-identical to banked R30 (depth-8 prefetch,
// raw-barrier WAITCH, DPP-exchange scan, physical-VGPR weights).

#define GBM 128
#define GBN 128
#define GBK 16
#define NWORK 31           // worker blocks (grid = NWORK+1)

typedef _Float16 h2_t __attribute__((ext_vector_type(2)));

__device__ __forceinline__ unsigned pk16(float a, float b) {
    h2_t p = {(_Float16)a, (_Float16)b};
    return __builtin_bit_cast(unsigned, p);
}

// ---------------- fallback serial GEMM (R25, unchanged) ----------------
__global__ __launch_bounds__(256) void gates_gemm(
    const float* __restrict__ A, const float* __restrict__ W,
    const float* __restrict__ bih, const float* __restrict__ bhh,
    float* __restrict__ XG, int T, int IN, int FH)
{
    __shared__ __align__(16) unsigned As16[GBK / 2][GBM];
    __shared__ __align__(16) unsigned Bs16[GBK / 2][GBN];
    const int bm = blockIdx.x * GBM;
    const int bn = blockIdx.y * GBN;
    const int tid = (int)threadIdx.x;
    const int tx = tid & 15, ty = tid >> 4;
    const int H = FH >> 2;

    const int row0 = tid >> 2;
    const int row1 = (tid + 256) >> 2;
    const int kq0  = (tid & 3) << 2;
    const int kp0  = kq0 >> 1;
    const size_t aoff0 = (size_t)(bm + row0) * IN;
    const size_t aoff1 = (size_t)(bm + row1) * IN;
    const size_t boff0 = (size_t)(bn + row0) * IN;
    const size_t boff1 = (size_t)(bn + row1) * IN;
    const bool bok0 = (bn + row0) < FH;
    const bool bok1 = (bn + row1) < FH;

    float acc[8][8];
    #pragma unroll
    for (int i = 0; i < 8; ++i)
        #pragma unroll
        for (int j = 0; j < 8; ++j) acc[i][j] = 0.f;

    float4 z4 = make_float4(0.f, 0.f, 0.f, 0.f);
    float4 av0 = z4, av1 = z4, bv0 = z4, bv1 = z4;
    {
        int gk = kq0;
        if (gk < IN) {
            av0 = *(const float4*)&A[aoff0 + gk];
            av1 = *(const float4*)&A[aoff1 + gk];
            if (bok0) bv0 = *(const float4*)&W[boff0 + gk];
            if (bok1) bv1 = *(const float4*)&W[boff1 + gk];
        }
    }
    for (int k0 = 0; k0 < IN; k0 += GBK) {
        As16[kp0 + 0][row0] = pk16(av0.x, av0.y);
        As16[kp0 + 1][row0] = pk16(av0.z, av0.w);
        As16[kp0 + 0][row1] = pk16(av1.x, av1.y);
        As16[kp0 + 1][row1] = pk16(av1.z, av1.w);
        Bs16[kp0 + 0][row0] = pk16(bv0.x, bv0.y);
        Bs16[kp0 + 1][row0] = pk16(bv0.z, bv0.w);
        Bs16[kp0 + 0][row1] = pk16(bv1.x, bv1.y);
        Bs16[kp0 + 1][row1] = pk16(bv1.z, bv1.w);
        __syncthreads();
        {
            int gk = k0 + GBK + kq0;
            float4 na0 = z4, na1 = z4, nb0 = z4, nb1 = z4;
            if (gk < IN) {
                na0 = *(const float4*)&A[aoff0 + gk];
                na1 = *(const float4*)&A[aoff1 + gk];
                if (bok0) nb0 = *(const float4*)&W[boff0 + gk];
                if (bok1) nb1 = *(const float4*)&W[boff1 + gk];
            }
            av0 = na0; av1 = na1; bv0 = nb0; bv1 = nb1;
        }
        #pragma unroll
        for (int kk2 = 0; kk2 < GBK / 2; ++kk2) {
            uint4 ua0 = *(const uint4*)&As16[kk2][ty * 4];
            uint4 ua1 = *(const uint4*)&As16[kk2][64 + ty * 4];
            uint4 ub0 = *(const uint4*)&Bs16[kk2][tx * 4];
            uint4 ub1 = *(const uint4*)&Bs16[kk2][64 + tx * 4];
            h2_t ap[8] = {
                __builtin_bit_cast(h2_t, ua0.x), __builtin_bit_cast(h2_t, ua0.y),
                __builtin_bit_cast(h2_t, ua0.z), __builtin_bit_cast(h2_t, ua0.w),
                __builtin_bit_cast(h2_t, ua1.x), __builtin_bit_cast(h2_t, ua1.y),
                __builtin_bit_cast(h2_t, ua1.z), __builtin_bit_cast(h2_t, ua1.w)};
            h2_t bp[8] = {
                __builtin_bit_cast(h2_t, ub0.x), __builtin_bit_cast(h2_t, ub0.y),
                __builtin_bit_cast(h2_t, ub0.z), __builtin_bit_cast(h2_t, ub0.w),
                __builtin_bit_cast(h2_t, ub1.x), __builtin_bit_cast(h2_t, ub1.y),
                __builtin_bit_cast(h2_t, ub1.z), __builtin_bit_cast(h2_t, ub1.w)};
            #pragma unroll
            for (int i = 0; i < 8; ++i)
                #pragma unroll
                for (int j = 0; j < 8; ++j)
                    acc[i][j] = __builtin_amdgcn_fdot2(ap[i], bp[j], acc[i][j], false);
        }
        __syncthreads();
    }
    #pragma unroll
    for (int i = 0; i < 8; ++i) {
        int r = bm + ((i < 4) ? (ty * 4 + i) : (64 + ty * 4 + (i - 4)));
        #pragma unroll
        for (int j = 0; j < 8; ++j) {
            int cidx = bn + ((j < 4) ? (tx * 4 + j) : (64 + tx * 4 + (j - 4)));
            if (cidx < FH) {
                int pc = 4 * (cidx % H) + cidx / H;
                XG[(size_t)r * FH + pc] = acc[i][j] + bih[cidx] + bhh[cidx];
            }
        }
    }
}

__global__ __launch_bounds__(64) void zero_flags(int* f, int n) {
    int i = (int)threadIdx.x;
    if (i < n) f[i] = 0;
}

// ---------------- scan machinery (R25-proven) ----------------
__device__ __forceinline__ float pack_pair(const float* rp, int k) {
    float a = 0.f, b = 0.f;
    if (k < 100) { a = rp[k]; b = rp[k + 1]; }
    h2_t p = {(_Float16)a, (_Float16)b};
    return __builtin_bit_cast(float, p);
}

#define INITW(R, V) \
    asm volatile("v_mov_b32 v" #R ", %0" :: "v"(V) : "v" #R)

#define DD(A, W, Hr) "v_dot2_f32_f16 v" #A ", v" #W ", v" #Hr ", v" #A "\n\t"

#define VCLOB \
  "v96","v97","v98","v99","v100","v101","v102","v103","v104","v105","v106",\
  "v107","v108","v109","v110","v111","v112","v113","v114","v115","v116",\
  "v117","v118","v119","v120","v121","v122","v123","v124","v125","v126",\
  "v127","v128","v129","v130","v131","v132","v133","v134","v135","v136",\
  "v137","v138","v139","v140","v141","v142","v143","v144","v145","v146",\
  "v147","v148","v149","v150","v151","v152","v153","v154","v155","v156",\
  "v157","v158","v159","v160","v161","v162","v163","v164","v165","v166",\
  "v167","v168","v169","v170","v171","v172","v173","v174","v175","v176",\
  "v177","v178","v179","v180","v181","v182","v183","v184","v185","v186",\
  "v187","v188","v189","v190","v191","v192","v193","v194","v195","v196",\
  "v197","v198","v199","v200","v201","v202","v203","v204","v205","v206",\
  "v207","v208","v209","v210","v211","v212","v213","v214","v215","v216",\
  "v217","v218","v219","v220","v221","v222","v223","v224","v225","v226",\
  "v227","v228","v229","v230","v231","v232","v233","v234","v235","v236",\
  "v237","v238","v239","v240","v241","v242","v243","v244","v245","v246",\
  "v247","v248","v249","v250","v251","v252","v253","v254","v255"

#define BAR() asm volatile("s_waitcnt lgkmcnt(0)\n\ts_barrier" ::: "memory")

// ---------------- fused kernel: block 0 = scan, blocks 1..NWORK = GEMM ----
__global__ __launch_bounds__(256, 1) void lstm_fused(
    const float* __restrict__ A,     // [T][IN]
    const float* __restrict__ Wih,   // [FH][IN]
    const float* __restrict__ bih,   // [FH]
    const float* __restrict__ bhh,   // [FH]
    float* __restrict__ XGp,         // [T][400] permuted (4u+g)
    const float* __restrict__ Whh,   // [400][100]
    const float* __restrict__ wlin,  // [100]
    const float* __restrict__ blin,  // [1]
    float* __restrict__ out,
    int* flags,                      // [T/128] chunk counters (or null)
    int T, int IN, int FH)
{
    __shared__ __align__(16) _Float16 hbuf[2][104];
    __shared__ float hfin[100];
    __shared__ __align__(16) unsigned As16[8][32];
    __shared__ __align__(16) unsigned Bs16[8][128];

    const int tid = (int)threadIdx.x;

    if (blockIdx.x != 0) {
        // ---------------- GEMM worker ----------------
        if (!flags) return;
        const int H = FH >> 2;
        const int ntile = (T >> 5) * 4;            // 32-row x 128-col tiles
        const int tx = tid & 31, ty = tid >> 5;
        const int sr   = tid >> 2;
        const int skq  = (tid & 3) << 2;
        const int skp  = skq >> 1;
        const bool aok = tid < 128;

        for (int tau = (int)blockIdx.x - 1; tau < ntile; tau += NWORK) {
            const int rb = tau >> 2, cb = tau & 3;
            const int bm = rb * 32, bn = cb * 128;
            const size_t aoff  = (size_t)(bm + sr) * IN;
            const size_t boff0 = (size_t)(bn + sr) * IN;
            const size_t boff1 = (size_t)(bn + 64 + sr) * IN;
            const bool bok0 = (bn + sr) < FH;
            const bool bok1 = (bn + 64 + sr) < FH;

            float acc[4][4];
            #pragma unroll
            for (int i = 0; i < 4; ++i)
                #pragma unroll
                for (int j = 0; j < 4; ++j) acc[i][j] = 0.f;

            float4 z4 = make_float4(0.f, 0.f, 0.f, 0.f);
            float4 av = z4, bv0 = z4, bv1 = z4;
            {
                int gk = skq;
                if (gk < IN) {
                    if (aok)  av  = *(const float4*)&A[aoff + gk];
                    if (bok0) bv0 = *(const float4*)&Wih[boff0 + gk];
                    if (bok1) bv1 = *(const float4*)&Wih[boff1 + gk];
                }
            }
            for (int k0 = 0; k0 < IN; k0 += 16) {
                if (aok) {
                    As16[skp + 0][sr] = pk16(av.x, av.y);
                    As16[skp + 1][sr] = pk16(av.z, av.w);
                }
                Bs16[skp + 0][sr]      = pk16(bv0.x, bv0.y);
                Bs16[skp + 1][sr]      = pk16(bv0.z, bv0.w);
                Bs16[skp + 0][64 + sr] = pk16(bv1.x, bv1.y);
                Bs16[skp + 1][64 + sr] = pk16(bv1.z, bv1.w);
                __syncthreads();
                {
                    int gk = k0 + 16 + skq;
                    float4 na = z4, nb0 = z4, nb1 = z4;
                    if (gk < IN) {
                        if (aok)  na  = *(const float4*)&A[aoff + gk];
                        if (bok0) nb0 = *(const float4*)&Wih[boff0 + gk];
                        if (bok1) nb1 = *(const float4*)&Wih[boff1 + gk];
                    }
                    av = na; bv0 = nb0; bv1 = nb1;
                }
                #pragma unroll
                for (int kk2 = 0; kk2 < 8; ++kk2) {
                    uint4 ua = *(const uint4*)&As16[kk2][ty * 4];
                    uint4 ub = *(const uint4*)&Bs16[kk2][tx * 4];
                    h2_t ap[4] = {
                        __builtin_bit_cast(h2_t, ua.x), __builtin_bit_cast(h2_t, ua.y),
                        __builtin_bit_cast(h2_t, ua.z), __builtin_bit_cast(h2_t, ua.w)};
                    h2_t bp[4] = {
                        __builtin_bit_cast(h2_t, ub.x), __builtin_bit_cast(h2_t, ub.y),
                        __builtin_bit_cast(h2_t, ub.z), __builtin_bit_cast(h2_t, ub.w)};
                    #pragma unroll
                    for (int i = 0; i < 4; ++i)
                        #pragma unroll
                        for (int j = 0; j < 4; ++j)
                            acc[i][j] = __builtin_amdgcn_fdot2(ap[i], bp[j], acc[i][j], false);
                }
                __syncthreads();
            }
            #pragma unroll
            for (int i = 0; i < 4; ++i) {
                int r = bm + ty * 4 + i;
                #pragma unroll
                for (int j = 0; j < 4; ++j) {
                    int cidx = bn + tx * 4 + j;
                    if (cidx < FH) {
                        int pc = 4 * (cidx % H) + cidx / H;
                        XGp[(size_t)r * FH + pc] = acc[i][j] + bih[cidx] + bhh[cidx];
                    }
                }
            }
            __threadfence();
            __syncthreads();
            if (tid == 0)
                __hip_atomic_fetch_add(flags + (rb >> 2), 1,
                                       __ATOMIC_RELEASE, __HIP_MEMORY_SCOPE_AGENT);
        }
        return;
    }

    // ---------------- scan (block 0) ----------------
    const int parity = tid & 1;
    const int p      = tid >> 1;
    const int pc     = (p < 100) ? p : 99;
    const bool act   = (parity == 0) && (p < 100);
    const float kk   = 1.f + (float)parity;

    const float* r0p = Whh + (size_t)(pc + parity * 200) * 100;
    const float* r1p = Whh + (size_t)(pc + 100 + parity * 200) * 100;

#define LW(j, R0, R1) { INITW(R0, pack_pair(r0p, 2*(j))); \
                        INITW(R1, pack_pair(r1p, 2*(j))); }
    LW(0,152,204)  LW(1,153,205)  LW(2,154,206)  LW(3,155,207)
    LW(4,156,208)  LW(5,157,209)  LW(6,158,210)  LW(7,159,211)
    LW(8,160,212)  LW(9,161,213)  LW(10,162,214) LW(11,163,215)
    LW(12,164,216) LW(13,165,217) LW(14,166,218) LW(15,167,219)
    LW(16,168,220) LW(17,169,221) LW(18,170,222) LW(19,171,223)
    LW(20,172,224) LW(21,173,225) LW(22,174,226) LW(23,175,227)
    LW(24,176,228) LW(25,177,229) LW(26,178,230) LW(27,179,231)
    LW(28,180,232) LW(29,181,233) LW(30,182,234) LW(31,183,235)
    LW(32,184,236) LW(33,185,237) LW(34,186,238) LW(35,187,239)
    LW(36,188,240) LW(37,189,241) LW(38,190,242) LW(39,191,243)
    LW(40,192,244) LW(41,193,245) LW(42,194,246) LW(43,195,247)
    LW(48,200,252) LW(44,196,248) LW(45,197,249) LW(46,198,250)
    LW(47,199,251) LW(49,201,253) LW(50,202,254) LW(51,203,255)
#undef LW

    if (tid < 104) { hbuf[0][tid] = (_Float16)0.f; hbuf[1][tid] = (_Float16)0.f; }

    const unsigned hb_base = (unsigned)(uintptr_t)&hbuf[0][0];
    const int xoff = 4 * pc + 2 * parity;

// wait until chunk c of xg is fully produced. RAW s_barrier (no vmcnt drain:
// in-flight xg prefetches survive) + per-thread acquire load (G16).
#define WAITCH(c) { \
    if (tid == 0) { \
        while (__hip_atomic_load(flags + (c), __ATOMIC_ACQUIRE, \
                                 __HIP_MEMORY_SCOPE_AGENT) < 16) { \
            __builtin_amdgcn_s_sleep(2); \
        } \
    } \
    asm volatile("s_barrier" ::: "memory"); \
    int f_ = __hip_atomic_load(flags + (c), __ATOMIC_ACQUIRE, \
                               __HIP_MEMORY_SCOPE_AGENT); \
    asm volatile("" :: "v"(f_)); }

#define XR(i) (*(const float2*)(XGp + (size_t)((i) < T ? (i) : (T - 1)) * 400 + xoff))

    if (flags) WAITCH(0);
    // depth-8 prefetch: 8 named registers (contention-tolerant ~8800 cyc)
    float2 xa = XR(0), xb = XR(1), xc = XR(2), xd = XR(3);
    float2 xe = XR(4), xf = XR(5), xg = XR(6), xh = XR(7);

    float c = 0.f, hlast = 0.f;
    int cur = 0;
    BAR();

#define MATVEC(G0, G1, HB, X0, X1) \
    asm volatile( \
        "v_mov_b32 v148, %[x0]\n\t" \
        "v_mov_b32 v149, %[x1]\n\t" \
        "v_mov_b32 v150, 0\n\t" \
        "v_mov_b32 v151, 0\n\t" \
        "ds_read_b128 v[96:99], %[hb]\n\t" \
        "ds_read_b128 v[100:103], %[hb] offset:16\n\t" \
        "ds_read_b128 v[104:107], %[hb] offset:32\n\t" \
        "ds_read_b128 v[108:111], %[hb] offset:48\n\t" \
        "ds_read_b128 v[112:115], %[hb] offset:64\n\t" \
        "ds_read_b128 v[116:119], %[hb] offset:80\n\t" \
        "ds_read_b128 v[120:123], %[hb] offset:96\n\t" \
        "ds_read_b128 v[124:127], %[hb] offset:112\n\t" \
        "ds_read_b128 v[128:131], %[hb] offset:128\n\t" \
        "ds_read_b128 v[132:135], %[hb] offset:144\n\t" \
        "ds_read_b128 v[136:139], %[hb] offset:160\n\t" \
        "ds_read_b128 v[140:143], %[hb] offset:176\n\t" \
        "ds_read_b128 v[144:147], %[hb] offset:192\n\t" \
        "s_waitcnt lgkmcnt(9)\n\t" \
        DD(148,152,96)  DD(149,204,96)  DD(150,153,97)  DD(151,205,97) \
        DD(148,154,98)  DD(149,206,98)  DD(150,155,99)  DD(151,207,99) \
        DD(148,156,100) DD(149,208,100) DD(150,157,101) DD(151,209,101) \
        DD(148,158,102) DD(149,210,102) DD(150,159,103) DD(151,211,103) \
        DD(148,160,104) DD(149,212,104) DD(150,161,105) DD(151,213,105) \
        DD(148,162,106) DD(149,214,106) DD(150,163,107) DD(151,215,107) \
        DD(148,164,108) DD(149,216,108) DD(150,165,109) DD(151,217,109) \
        DD(148,166,110) DD(149,218,110) DD(150,167,111) DD(151,219,111) \
        "s_waitcnt lgkmcnt(5)\n\t" \
        DD(148,168,112) DD(149,220,112) DD(150,169,113) DD(151,221,113) \
        DD(148,170,114) DD(149,222,114) DD(150,171,115) DD(151,223,115) \
        DD(148,172,116) DD(149,224,116) DD(150,173,117) DD(151,225,117) \
        DD(148,174,118) DD(149,226,118) DD(150,175,119) DD(151,227,119) \
        DD(148,176,120) DD(149,228,120) DD(150,177,121) DD(151,229,121) \
        DD(148,178,122) DD(149,230,122) DD(150,179,123) DD(151,231,123) \
        DD(148,180,124) DD(149,232,124) DD(150,181,125) DD(151,233,125) \
        DD(148,182,126) DD(149,234,126) DD(150,183,127) DD(151,235,127) \
        "s_waitcnt lgkmcnt(1)\n\t" \
        DD(148,184,128) DD(149,236,128) DD(150,185,129) DD(151,237,129) \
        DD(148,186,130) DD(149,238,130) DD(150,187,131) DD(151,239,131) \
        DD(148,188,132) DD(149,240,132) DD(150,189,133) DD(151,241,133) \
        DD(148,190,134) DD(149,242,134) DD(150,191,135) DD(151,243,135) \
        DD(148,192,136) DD(149,244,136) DD(150,193,137) DD(151,245,137) \
        DD(148,194,138) DD(149,246,138) DD(150,195,139) DD(151,247,139) \
        DD(148,196,140) DD(149,248,140) DD(150,197,141) DD(151,249,141) \
        DD(148,198,142) DD(149,250,142) DD(150,199,143) DD(151,251,143) \
        "s_waitcnt lgkmcnt(0)\n\t" \
        DD(148,200,144) DD(149,252,144) DD(150,201,145) DD(151,253,145) \
        DD(148,202,146) DD(149,254,146) DD(150,203,147) DD(151,255,147) \
        "v_add_f32 %[g0], v148, v150\n\t" \
        "v_add_f32 %[g1], v149, v151" \
        : [g0]"=v"(G0), [g1]"=v"(G1) \
        : [hb]"v"(HB), [x0]"v"(X0), [x1]"v"(X1) \
        : VCLOB, "memory")

#define SUBSTEP(XP, TNEXT) { \
    unsigned hb_ = hb_base + (unsigned)(cur * 208); \
    float g0, g1; \
    MATVEC(g0, g1, hb_, XP.x, XP.y); \
    XP = XR(TNEXT);   /* direct load into named reg; next use 8 steps away */ \
    float e0  = __expf(kk * g0); \
    float t0v = 1.f - kk * __builtin_amdgcn_rcpf(e0 + 1.f); \
    float e1  = __expf(-g1); \
    float t1v = __builtin_amdgcn_rcpf(1.f + e1); \
    float rg_, ro_; \
    asm volatile("s_nop 3\n\t" \
                 "v_mov_b32 %0, %2 quad_perm:[1,0,3,2] row_mask:0xf bank_mask:0xf\n\t" \
                 "v_mov_b32 %1, %3 quad_perm:[1,0,3,2] row_mask:0xf bank_mask:0xf" \
                 : "=v"(rg_), "=v"(ro_) : "v"(t0v), "v"(t1v)); \
    c = fmaf(t1v, c, t0v * rg_); \
    float e2 = __expf(2.f * c); \
    float th = 1.f - 2.f * __builtin_amdgcn_rcpf(e2 + 1.f); \
    float hv_ = ro_ * th; \
    if (act) { hlast = hv_; hbuf[cur ^ 1][p] = (_Float16)hv_; } \
    BAR(); \
    cur ^= 1; }

    for (int t = 0; t < T; t += 8) {
        if (flags && (t & 127) == 120 && (t + 8) < T) WAITCH((t + 8) >> 7);
        SUBSTEP(xa, t + 8)
        SUBSTEP(xb, t + 9)
        SUBSTEP(xc, t + 10)
        SUBSTEP(xd, t + 11)
        SUBSTEP(xe, t + 12)
        SUBSTEP(xf, t + 13)
        SUBSTEP(xg, t + 14)
        SUBSTEP(xh, t + 15)
    }
#undef SUBSTEP
#undef XR
#undef WAITCH

    if (act) hfin[p] = hlast * wlin[p];
    __syncthreads();
    if (tid == 0) {
        float s = blin[0];
        for (int k = 0; k < 100; ++k) s += hfin[k];
        out[0] = s;
    }
}

extern "C" void kernel_launch(void* const* d_in, const int* in_sizes, int n_in,
                              void* d_out, int out_size, void* d_ws, size_t ws_size,
                              hipStream_t stream) {
    const float* input = (const float*)d_in[0];  // [T][IN]
    const float* w_ih  = (const float*)d_in[1];  // [4H][IN]
    const float* w_hh  = (const float*)d_in[2];  // [4H][H]
    const float* b_ih  = (const float*)d_in[3];  // [4H]
    const float* b_hh  = (const float*)d_in[4];  // [4H]
    const float* w_lin = (const float*)d_in[5];  // [H]
    const float* b_lin = (const float*)d_in[6];  // [1]
    float* out = (float*)d_out;

    const int FH = in_sizes[3];            // 400
    const int IN = in_sizes[1] / FH;       // 3000
    const int T  = in_sizes[0] / IN;       // 8192

    float* xg = (float*)d_ws;              // [T][FH] = 13.1 MB (permuted)
    const size_t xg_bytes = (size_t)T * FH * 4;
    const int nchunks = (T + 127) >> 7;    // 64

    const bool overlap = (ws_size >= xg_bytes + 256) && (T % 128 == 0);
    if (overlap) {
        int* flags = (int*)((char*)d_ws + xg_bytes);
        zero_flags<<<1, 64, 0, stream>>>(flags, nchunks);
        lstm_fused<<<NWORK + 1, 256, 0, stream>>>(input, w_ih, b_ih, b_hh, xg,
                                                  w_hh, w_lin, b_lin, out, flags,
                                                  T, IN, FH);
    } else {
        dim3 grid((T + GBM - 1) / GBM, (FH + GBN - 1) / GBN);
        gates_gemm<<<grid, 256, 0, stream>>>(input, w_ih, b_ih, b_hh, xg, T, IN, FH);
        lstm_fused<<<1, 256, 0, stream>>>(input, w_ih, b_ih, b_hh, xg,
                                          w_hh, w_lin, b_lin, out, nullptr,
                                          T, IN, FH);
    }
}

// Round 32
// 3695.091 us; speedup vs baseline: 1.0161x; 1.0161x over previous
//
#include <hip/hip_runtime.h>
#include <hip/hip_bf16.h>

// LSTM: T=8192, IN=3000, H=100 (4H=400), torch gate order i,f,g,o.
// ROUND-32 (FINAL RESTORE): worker-count dial is a measured U-curve
// (NWORK 255->3810us, 127->3784, 63->3760 fused [3698 total, session
// best], 31->4042 [scan starts waiting on tail chunks]). Restoring the
// optimum NWORK=63 artifact (banked R30) verbatim.
// Architecture: one fused kernel; block 0 = single-CU scan (weights in
// PHYSICAL VGPRs v152..v255, 100-unit lane-pair dot2 matvec in one asm
// block, DPP quad_perm gate exchange, depth-8 named-register xg prefetch,
// lgkmcnt-only barriers); blocks 1..63 = f16-dot2 GEMM producing xg in
// 32x128 tiles with per-128-row-chunk release/acquire flags; raw-barrier
// WAITCH keeps prefetches alive. GEMM fully hidden under the 8192-step
// serial recurrence (~1030 cyc/step).

#define GBM 128
#define GBN 128
#define GBK 16
#define NWORK 63           // worker blocks (grid = NWORK+1) -- measured optimum

typedef _Float16 h2_t __attribute__((ext_vector_type(2)));

__device__ __forceinline__ unsigned pk16(float a, float b) {
    h2_t p = {(_Float16)a, (_Float16)b};
    return __builtin_bit_cast(unsigned, p);
}

// ---------------- fallback serial GEMM (R25, unchanged) ----------------
__global__ __launch_bounds__(256) void gates_gemm(
    const float* __restrict__ A, const float* __restrict__ W,
    const float* __restrict__ bih, const float* __restrict__ bhh,
    float* __restrict__ XG, int T, int IN, int FH)
{
    __shared__ __align__(16) unsigned As16[GBK / 2][GBM];
    __shared__ __align__(16) unsigned Bs16[GBK / 2][GBN];
    const int bm = blockIdx.x * GBM;
    const int bn = blockIdx.y * GBN;
    const int tid = (int)threadIdx.x;
    const int tx = tid & 15, ty = tid >> 4;
    const int H = FH >> 2;

    const int row0 = tid >> 2;
    const int row1 = (tid + 256) >> 2;
    const int kq0  = (tid & 3) << 2;
    const int kp0  = kq0 >> 1;
    const size_t aoff0 = (size_t)(bm + row0) * IN;
    const size_t aoff1 = (size_t)(bm + row1) * IN;
    const size_t boff0 = (size_t)(bn + row0) * IN;
    const size_t boff1 = (size_t)(bn + row1) * IN;
    const bool bok0 = (bn + row0) < FH;
    const bool bok1 = (bn + row1) < FH;

    float acc[8][8];
    #pragma unroll
    for (int i = 0; i < 8; ++i)
        #pragma unroll
        for (int j = 0; j < 8; ++j) acc[i][j] = 0.f;

    float4 z4 = make_float4(0.f, 0.f, 0.f, 0.f);
    float4 av0 = z4, av1 = z4, bv0 = z4, bv1 = z4;
    {
        int gk = kq0;
        if (gk < IN) {
            av0 = *(const float4*)&A[aoff0 + gk];
            av1 = *(const float4*)&A[aoff1 + gk];
            if (bok0) bv0 = *(const float4*)&W[boff0 + gk];
            if (bok1) bv1 = *(const float4*)&W[boff1 + gk];
        }
    }
    for (int k0 = 0; k0 < IN; k0 += GBK) {
        As16[kp0 + 0][row0] = pk16(av0.x, av0.y);
        As16[kp0 + 1][row0] = pk16(av0.z, av0.w);
        As16[kp0 + 0][row1] = pk16(av1.x, av1.y);
        As16[kp0 + 1][row1] = pk16(av1.z, av1.w);
        Bs16[kp0 + 0][row0] = pk16(bv0.x, bv0.y);
        Bs16[kp0 + 1][row0] = pk16(bv0.z, bv0.w);
        Bs16[kp0 + 0][row1] = pk16(bv1.x, bv1.y);
        Bs16[kp0 + 1][row1] = pk16(bv1.z, bv1.w);
        __syncthreads();
        {
            int gk = k0 + GBK + kq0;
            float4 na0 = z4, na1 = z4, nb0 = z4, nb1 = z4;
            if (gk < IN) {
                na0 = *(const float4*)&A[aoff0 + gk];
                na1 = *(const float4*)&A[aoff1 + gk];
                if (bok0) nb0 = *(const float4*)&W[boff0 + gk];
                if (bok1) nb1 = *(const float4*)&W[boff1 + gk];
            }
            av0 = na0; av1 = na1; bv0 = nb0; bv1 = nb1;
        }
        #pragma unroll
        for (int kk2 = 0; kk2 < GBK / 2; ++kk2) {
            uint4 ua0 = *(const uint4*)&As16[kk2][ty * 4];
            uint4 ua1 = *(const uint4*)&As16[kk2][64 + ty * 4];
            uint4 ub0 = *(const uint4*)&Bs16[kk2][tx * 4];
            uint4 ub1 = *(const uint4*)&Bs16[kk2][64 + tx * 4];
            h2_t ap[8] = {
                __builtin_bit_cast(h2_t, ua0.x), __builtin_bit_cast(h2_t, ua0.y),
                __builtin_bit_cast(h2_t, ua0.z), __builtin_bit_cast(h2_t, ua0.w),
                __builtin_bit_cast(h2_t, ua1.x), __builtin_bit_cast(h2_t, ua1.y),
                __builtin_bit_cast(h2_t, ua1.z), __builtin_bit_cast(h2_t, ua1.w)};
            h2_t bp[8] = {
                __builtin_bit_cast(h2_t, ub0.x), __builtin_bit_cast(h2_t, ub0.y),
                __builtin_bit_cast(h2_t, ub0.z), __builtin_bit_cast(h2_t, ub0.w),
                __builtin_bit_cast(h2_t, ub1.x), __builtin_bit_cast(h2_t, ub1.y),
                __builtin_bit_cast(h2_t, ub1.z), __builtin_bit_cast(h2_t, ub1.w)};
            #pragma unroll
            for (int i = 0; i < 8; ++i)
                #pragma unroll
                for (int j = 0; j < 8; ++j)
                    acc[i][j] = __builtin_amdgcn_fdot2(ap[i], bp[j], acc[i][j], false);
        }
        __syncthreads();
    }
    #pragma unroll
    for (int i = 0; i < 8; ++i) {
        int r = bm + ((i < 4) ? (ty * 4 + i) : (64 + ty * 4 + (i - 4)));
        #pragma unroll
        for (int j = 0; j < 8; ++j) {
            int cidx = bn + ((j < 4) ? (tx * 4 + j) : (64 + tx * 4 + (j - 4)));
            if (cidx < FH) {
                int pc = 4 * (cidx % H) + cidx / H;
                XG[(size_t)r * FH + pc] = acc[i][j] + bih[cidx] + bhh[cidx];
            }
        }
    }
}

__global__ __launch_bounds__(64) void zero_flags(int* f, int n) {
    int i = (int)threadIdx.x;
    if (i < n) f[i] = 0;
}

// ---------------- scan machinery (R25-proven) ----------------
__device__ __forceinline__ float pack_pair(const float* rp, int k) {
    float a = 0.f, b = 0.f;
    if (k < 100) { a = rp[k]; b = rp[k + 1]; }
    h2_t p = {(_Float16)a, (_Float16)b};
    return __builtin_bit_cast(float, p);
}

#define INITW(R, V) \
    asm volatile("v_mov_b32 v" #R ", %0" :: "v"(V) : "v" #R)

#define DD(A, W, Hr) "v_dot2_f32_f16 v" #A ", v" #W ", v" #Hr ", v" #A "\n\t"

#define VCLOB \
  "v96","v97","v98","v99","v100","v101","v102","v103","v104","v105","v106",\
  "v107","v108","v109","v110","v111","v112","v113","v114","v115","v116",\
  "v117","v118","v119","v120","v121","v122","v123","v124","v125","v126",\
  "v127","v128","v129","v130","v131","v132","v133","v134","v135","v136",\
  "v137","v138","v139","v140","v141","v142","v143","v144","v145","v146",\
  "v147","v148","v149","v150","v151","v152","v153","v154","v155","v156",\
  "v157","v158","v159","v160","v161","v162","v163","v164","v165","v166",\
  "v167","v168","v169","v170","v171","v172","v173","v174","v175","v176",\
  "v177","v178","v179","v180","v181","v182","v183","v184","v185","v186",\
  "v187","v188","v189","v190","v191","v192","v193","v194","v195","v196",\
  "v197","v198","v199","v200","v201","v202","v203","v204","v205","v206",\
  "v207","v208","v209","v210","v211","v212","v213","v214","v215","v216",\
  "v217","v218","v219","v220","v221","v222","v223","v224","v225","v226",\
  "v227","v228","v229","v230","v231","v232","v233","v234","v235","v236",\
  "v237","v238","v239","v240","v241","v242","v243","v244","v245","v246",\
  "v247","v248","v249","v250","v251","v252","v253","v254","v255"

#define BAR() asm volatile("s_waitcnt lgkmcnt(0)\n\ts_barrier" ::: "memory")

// ---------------- fused kernel: block 0 = scan, blocks 1..NWORK = GEMM ----
__global__ __launch_bounds__(256, 1) void lstm_fused(
    const float* __restrict__ A,     // [T][IN]
    const float* __restrict__ Wih,   // [FH][IN]
    const float* __restrict__ bih,   // [FH]
    const float* __restrict__ bhh,   // [FH]
    float* __restrict__ XGp,         // [T][400] permuted (4u+g)
    const float* __restrict__ Whh,   // [400][100]
    const float* __restrict__ wlin,  // [100]
    const float* __restrict__ blin,  // [1]
    float* __restrict__ out,
    int* flags,                      // [T/128] chunk counters (or null)
    int T, int IN, int FH)
{
    __shared__ __align__(16) _Float16 hbuf[2][104];
    __shared__ float hfin[100];
    __shared__ __align__(16) unsigned As16[8][32];
    __shared__ __align__(16) unsigned Bs16[8][128];

    const int tid = (int)threadIdx.x;

    if (blockIdx.x != 0) {
        // ---------------- GEMM worker ----------------
        if (!flags) return;
        const int H = FH >> 2;
        const int ntile = (T >> 5) * 4;            // 32-row x 128-col tiles
        const int tx = tid & 31, ty = tid >> 5;
        const int sr   = tid >> 2;
        const int skq  = (tid & 3) << 2;
        const int skp  = skq >> 1;
        const bool aok = tid < 128;

        for (int tau = (int)blockIdx.x - 1; tau < ntile; tau += NWORK) {
            const int rb = tau >> 2, cb = tau & 3;
            const int bm = rb * 32, bn = cb * 128;
            const size_t aoff  = (size_t)(bm + sr) * IN;
            const size_t boff0 = (size_t)(bn + sr) * IN;
            const size_t boff1 = (size_t)(bn + 64 + sr) * IN;
            const bool bok0 = (bn + sr) < FH;
            const bool bok1 = (bn + 64 + sr) < FH;

            float acc[4][4];
            #pragma unroll
            for (int i = 0; i < 4; ++i)
                #pragma unroll
                for (int j = 0; j < 4; ++j) acc[i][j] = 0.f;

            float4 z4 = make_float4(0.f, 0.f, 0.f, 0.f);
            float4 av = z4, bv0 = z4, bv1 = z4;
            {
                int gk = skq;
                if (gk < IN) {
                    if (aok)  av  = *(const float4*)&A[aoff + gk];
                    if (bok0) bv0 = *(const float4*)&Wih[boff0 + gk];
                    if (bok1) bv1 = *(const float4*)&Wih[boff1 + gk];
                }
            }
            for (int k0 = 0; k0 < IN; k0 += 16) {
                if (aok) {
                    As16[skp + 0][sr] = pk16(av.x, av.y);
                    As16[skp + 1][sr] = pk16(av.z, av.w);
                }
                Bs16[skp + 0][sr]      = pk16(bv0.x, bv0.y);
                Bs16[skp + 1][sr]      = pk16(bv0.z, bv0.w);
                Bs16[skp + 0][64 + sr] = pk16(bv1.x, bv1.y);
                Bs16[skp + 1][64 + sr] = pk16(bv1.z, bv1.w);
                __syncthreads();
                {
                    int gk = k0 + 16 + skq;
                    float4 na = z4, nb0 = z4, nb1 = z4;
                    if (gk < IN) {
                        if (aok)  na  = *(const float4*)&A[aoff + gk];
                        if (bok0) nb0 = *(const float4*)&Wih[boff0 + gk];
                        if (bok1) nb1 = *(const float4*)&Wih[boff1 + gk];
                    }
                    av = na; bv0 = nb0; bv1 = nb1;
                }
                #pragma unroll
                for (int kk2 = 0; kk2 < 8; ++kk2) {
                    uint4 ua = *(const uint4*)&As16[kk2][ty * 4];
                    uint4 ub = *(const uint4*)&Bs16[kk2][tx * 4];
                    h2_t ap[4] = {
                        __builtin_bit_cast(h2_t, ua.x), __builtin_bit_cast(h2_t, ua.y),
                        __builtin_bit_cast(h2_t, ua.z), __builtin_bit_cast(h2_t, ua.w)};
                    h2_t bp[4] = {
                        __builtin_bit_cast(h2_t, ub.x), __builtin_bit_cast(h2_t, ub.y),
                        __builtin_bit_cast(h2_t, ub.z), __builtin_bit_cast(h2_t, ub.w)};
                    #pragma unroll
                    for (int i = 0; i < 4; ++i)
                        #pragma unroll
                        for (int j = 0; j < 4; ++j)
                            acc[i][j] = __builtin_amdgcn_fdot2(ap[i], bp[j], acc[i][j], false);
                }
                __syncthreads();
            }
            #pragma unroll
            for (int i = 0; i < 4; ++i) {
                int r = bm + ty * 4 + i;
                #pragma unroll
                for (int j = 0; j < 4; ++j) {
                    int cidx = bn + tx * 4 + j;
                    if (cidx < FH) {
                        int pc = 4 * (cidx % H) + cidx / H;
                        XGp[(size_t)r * FH + pc] = acc[i][j] + bih[cidx] + bhh[cidx];
                    }
                }
            }
            __threadfence();
            __syncthreads();
            if (tid == 0)
                __hip_atomic_fetch_add(flags + (rb >> 2), 1,
                                       __ATOMIC_RELEASE, __HIP_MEMORY_SCOPE_AGENT);
        }
        return;
    }

    // ---------------- scan (block 0) ----------------
    const int parity = tid & 1;
    const int p      = tid >> 1;
    const int pc     = (p < 100) ? p : 99;
    const bool act   = (parity == 0) && (p < 100);
    const float kk   = 1.f + (float)parity;

    const float* r0p = Whh + (size_t)(pc + parity * 200) * 100;
    const float* r1p = Whh + (size_t)(pc + 100 + parity * 200) * 100;

#define LW(j, R0, R1) { INITW(R0, pack_pair(r0p, 2*(j))); \
                        INITW(R1, pack_pair(r1p, 2*(j))); }
    LW(0,152,204)  LW(1,153,205)  LW(2,154,206)  LW(3,155,207)
    LW(4,156,208)  LW(5,157,209)  LW(6,158,210)  LW(7,159,211)
    LW(8,160,212)  LW(9,161,213)  LW(10,162,214) LW(11,163,215)
    LW(12,164,216) LW(13,165,217) LW(14,166,218) LW(15,167,219)
    LW(16,168,220) LW(17,169,221) LW(18,170,222) LW(19,171,223)
    LW(20,172,224) LW(21,173,225) LW(22,174,226) LW(23,175,227)
    LW(24,176,228) LW(25,177,229) LW(26,178,230) LW(27,179,231)
    LW(28,180,232) LW(29,181,233) LW(30,182,234) LW(31,183,235)
    LW(32,184,236) LW(33,185,237) LW(34,186,238) LW(35,187,239)
    LW(36,188,240) LW(37,189,241) LW(38,190,242) LW(39,191,243)
    LW(40,192,244) LW(41,193,245) LW(42,194,246) LW(43,195,247)
    LW(48,200,252) LW(44,196,248) LW(45,197,249) LW(46,198,250)
    LW(47,199,251) LW(49,201,253) LW(50,202,254) LW(51,203,255)
#undef LW

    if (tid < 104) { hbuf[0][tid] = (_Float16)0.f; hbuf[1][tid] = (_Float16)0.f; }

    const unsigned hb_base = (unsigned)(uintptr_t)&hbuf[0][0];
    const int xoff = 4 * pc + 2 * parity;

// wait until chunk c of xg is fully produced. RAW s_barrier (no vmcnt drain:
// in-flight xg prefetches survive) + per-thread acquire load (G16).
#define WAITCH(c) { \
    if (tid == 0) { \
        while (__hip_atomic_load(flags + (c), __ATOMIC_ACQUIRE, \
                                 __HIP_MEMORY_SCOPE_AGENT) < 16) { \
            __builtin_amdgcn_s_sleep(2); \
        } \
    } \
    asm volatile("s_barrier" ::: "memory"); \
    int f_ = __hip_atomic_load(flags + (c), __ATOMIC_ACQUIRE, \
                               __HIP_MEMORY_SCOPE_AGENT); \
    asm volatile("" :: "v"(f_)); }

#define XR(i) (*(const float2*)(XGp + (size_t)((i) < T ? (i) : (T - 1)) * 400 + xoff))

    if (flags) WAITCH(0);
    // depth-8 prefetch: 8 named registers (contention-tolerant ~8800 cyc)
    float2 xa = XR(0), xb = XR(1), xc = XR(2), xd = XR(3);
    float2 xe = XR(4), xf = XR(5), xg = XR(6), xh = XR(7);

    float c = 0.f, hlast = 0.f;
    int cur = 0;
    BAR();

#define MATVEC(G0, G1, HB, X0, X1) \
    asm volatile( \
        "v_mov_b32 v148, %[x0]\n\t" \
        "v_mov_b32 v149, %[x1]\n\t" \
        "v_mov_b32 v150, 0\n\t" \
        "v_mov_b32 v151, 0\n\t" \
        "ds_read_b128 v[96:99], %[hb]\n\t" \
        "ds_read_b128 v[100:103], %[hb] offset:16\n\t" \
        "ds_read_b128 v[104:107], %[hb] offset:32\n\t" \
        "ds_read_b128 v[108:111], %[hb] offset:48\n\t" \
        "ds_read_b128 v[112:115], %[hb] offset:64\n\t" \
        "ds_read_b128 v[116:119], %[hb] offset:80\n\t" \
        "ds_read_b128 v[120:123], %[hb] offset:96\n\t" \
        "ds_read_b128 v[124:127], %[hb] offset:112\n\t" \
        "ds_read_b128 v[128:131], %[hb] offset:128\n\t" \
        "ds_read_b128 v[132:135], %[hb] offset:144\n\t" \
        "ds_read_b128 v[136:139], %[hb] offset:160\n\t" \
        "ds_read_b128 v[140:143], %[hb] offset:176\n\t" \
        "ds_read_b128 v[144:147], %[hb] offset:192\n\t" \
        "s_waitcnt lgkmcnt(9)\n\t" \
        DD(148,152,96)  DD(149,204,96)  DD(150,153,97)  DD(151,205,97) \
        DD(148,154,98)  DD(149,206,98)  DD(150,155,99)  DD(151,207,99) \
        DD(148,156,100) DD(149,208,100) DD(150,157,101) DD(151,209,101) \
        DD(148,158,102) DD(149,210,102) DD(150,159,103) DD(151,211,103) \
        DD(148,160,104) DD(149,212,104) DD(150,161,105) DD(151,213,105) \
        DD(148,162,106) DD(149,214,106) DD(150,163,107) DD(151,215,107) \
        DD(148,164,108) DD(149,216,108) DD(150,165,109) DD(151,217,109) \
        DD(148,166,110) DD(149,218,110) DD(150,167,111) DD(151,219,111) \
        "s_waitcnt lgkmcnt(5)\n\t" \
        DD(148,168,112) DD(149,220,112) DD(150,169,113) DD(151,221,113) \
        DD(148,170,114) DD(149,222,114) DD(150,171,115) DD(151,223,115) \
        DD(148,172,116) DD(149,224,116) DD(150,173,117) DD(151,225,117) \
        DD(148,174,118) DD(149,226,118) DD(150,175,119) DD(151,227,119) \
        DD(148,176,120) DD(149,228,120) DD(150,177,121) DD(151,229,121) \
        DD(148,178,122) DD(149,230,122) DD(150,179,123) DD(151,231,123) \
        DD(148,180,124) DD(149,232,124) DD(150,181,125) DD(151,233,125) \
        DD(148,182,126) DD(149,234,126) DD(150,183,127) DD(151,235,127) \
        "s_waitcnt lgkmcnt(1)\n\t" \
        DD(148,184,128) DD(149,236,128) DD(150,185,129) DD(151,237,129) \
        DD(148,186,130) DD(149,238,130) DD(150,187,131) DD(151,239,131) \
        DD(148,188,132) DD(149,240,132) DD(150,189,133) DD(151,241,133) \
        DD(148,190,134) DD(149,242,134) DD(150,191,135) DD(151,243,135) \
        DD(148,192,136) DD(149,244,136) DD(150,193,137) DD(151,245,137) \
        DD(148,194,138) DD(149,246,138) DD(150,195,139) DD(151,247,139) \
        DD(148,196,140) DD(149,248,140) DD(150,197,141) DD(151,249,141) \
        DD(148,198,142) DD(149,250,142) DD(150,199,143) DD(151,251,143) \
        "s_waitcnt lgkmcnt(0)\n\t" \
        DD(148,200,144) DD(149,252,144) DD(150,201,145) DD(151,253,145) \
        DD(148,202,146) DD(149,254,146) DD(150,203,147) DD(151,255,147) \
        "v_add_f32 %[g0], v148, v150\n\t" \
        "v_add_f32 %[g1], v149, v151" \
        : [g0]"=v"(G0), [g1]"=v"(G1) \
        : [hb]"v"(HB), [x0]"v"(X0), [x1]"v"(X1) \
        : VCLOB, "memory")

#define SUBSTEP(XP, TNEXT) { \
    unsigned hb_ = hb_base + (unsigned)(cur * 208); \
    float g0, g1; \
    MATVEC(g0, g1, hb_, XP.x, XP.y); \
    XP = XR(TNEXT);   /* direct load into named reg; next use 8 steps away */ \
    float e0  = __expf(kk * g0); \
    float t0v = 1.f - kk * __builtin_amdgcn_rcpf(e0 + 1.f); \
    float e1  = __expf(-g1); \
    float t1v = __builtin_amdgcn_rcpf(1.f + e1); \
    float rg_, ro_; \
    asm volatile("s_nop 3\n\t" \
                 "v_mov_b32 %0, %2 quad_perm:[1,0,3,2] row_mask:0xf bank_mask:0xf\n\t" \
                 "v_mov_b32 %1, %3 quad_perm:[1,0,3,2] row_mask:0xf bank_mask:0xf" \
                 : "=v"(rg_), "=v"(ro_) : "v"(t0v), "v"(t1v)); \
    c = fmaf(t1v, c, t0v * rg_); \
    float e2 = __expf(2.f * c); \
    float th = 1.f - 2.f * __builtin_amdgcn_rcpf(e2 + 1.f); \
    float hv_ = ro_ * th; \
    if (act) { hlast = hv_; hbuf[cur ^ 1][p] = (_Float16)hv_; } \
    BAR(); \
    cur ^= 1; }

    for (int t = 0; t < T; t += 8) {
        if (flags && (t & 127) == 120 && (t + 8) < T) WAITCH((t + 8) >> 7);
        SUBSTEP(xa, t + 8)
        SUBSTEP(xb, t + 9)
        SUBSTEP(xc, t + 10)
        SUBSTEP(xd, t + 11)
        SUBSTEP(xe, t + 12)
        SUBSTEP(xf, t + 13)
        SUBSTEP(xg, t + 14)
        SUBSTEP(xh, t + 15)
    }
#undef SUBSTEP
#undef XR
#undef WAITCH

    if (act) hfin[p] = hlast * wlin[p];
    __syncthreads();
    if (tid == 0) {
        float s = blin[0];
        for (int k = 0; k < 100; ++k) s += hfin[k];
        out[0] = s;
    }
}

extern "C" void kernel_launch(void* const* d_in, const int* in_sizes, int n_in,
                              void* d_out, int out_size, void* d_ws, size_t ws_size,
                              hipStream_t stream) {
    const float* input = (const float*)d_in[0];  // [T][IN]
    const float* w_ih  = (const float*)d_in[1];  // [4H][IN]
    const float* w_hh  = (const float*)d_in[2];  // [4H][H]
    const float* b_ih  = (const float*)d_in[3];  // [4H]
    const float* b_hh  = (const float*)d_in[4];  // [4H]
    const float* w_lin = (const float*)d_in[5];  // [H]
    const float* b_lin = (const float*)d_in[6];  // [1]
    float* out = (float*)d_out;

    const int FH = in_sizes[3];            // 400
    const int IN = in_sizes[1] / FH;       // 3000
    const int T  = in_sizes[0] / IN;       // 8192

    float* xg = (float*)d_ws;              // [T][FH] = 13.1 MB (permuted)
    const size_t xg_bytes = (size_t)T * FH * 4;
    const int nchunks = (T + 127) >> 7;    // 64

    const bool overlap = (ws_size >= xg_bytes + 256) && (T % 128 == 0);
    if (overlap) {
        int* flags = (int*)((char*)d_ws + xg_bytes);
        zero_flags<<<1, 64, 0, stream>>>(flags, nchunks);
        lstm_fused<<<NWORK + 1, 256, 0, stream>>>(input, w_ih, b_ih, b_hh, xg,
                                                  w_hh, w_lin, b_lin, out, flags,
                                                  T, IN, FH);
    } else {
        dim3 grid((T + GBM - 1) / GBM, (FH + GBN - 1) / GBN);
        gates_gemm<<<grid, 256, 0, stream>>>(input, w_ih, b_ih, b_hh, xg, T, IN, FH);
        lstm_fused<<<1, 256, 0, stream>>>(input, w_ih, b_ih, b_hh, xg,
                                          w_hh, w_lin, b_lin, out, nullptr,
                                          T, IN, FH);
    }
}